// Round 5
// baseline (279.226 us; speedup 1.0000x reference)
//
#include <hip/hip_runtime.h>

#define NN 50000
#define NE 400000
#define SCAN_N (2 * NN)
#define SA_BLOCKS ((SCAN_N + 255) / 256)   // 391
#define NPB 32                             // src nodes per fused block
#define YSTRIDE 276                        // 272 + pad: 8 nodes/wave hit disjoint bank quads
#define MAXSLOT 1024                       // max edges per 32-node block (avg 256, >30 sigma margin)

// ws layout (4B units):
//   msg1     float [16*NE]
//   msg2     float [16*NE]
//   h1       float [16*NN]
//   offs_all int   [2NN+1]   (src offsets [0..NN]; dst offsets at [NN..2NN], values offset by NE)
//   cursor   int   [2NN]
//   ordsrc   int2  [NE]      per src slot: {edge id, dst slot}
//   bsum     int   [512]

// ---------------------------------------------------------------------------
// CSR build: combined src+dst histogram -> 3-phase scan over 2N -> fill
// ---------------------------------------------------------------------------
__global__ __launch_bounds__(256) void hist2_kernel(
    const int* __restrict__ eidx, int* __restrict__ cnt)
{
    int e = blockIdx.x * 256 + threadIdx.x;
    if (e < NE) {
        atomicAdd(&cnt[eidx[e]], 1);
        atomicAdd(&cnt[NN + eidx[NE + e]], 1);
    }
}

template <int NT>
__device__ __forceinline__ int block_excl_scan(int v, int tid)
{
    __shared__ int wsum[NT / 64];
    int lane = tid & 63, w = tid >> 6;
    int incl = v;
#pragma unroll
    for (int d = 1; d < 64; d <<= 1) {
        int t = __shfl_up(incl, d, 64);
        if (lane >= d) incl += t;
    }
    if (lane == 63) wsum[w] = incl;
    __syncthreads();
    if (tid == 0) {
        int s = 0;
#pragma unroll
        for (int k = 0; k < NT / 64; ++k) { int t = wsum[k]; wsum[k] = s; s += t; }
    }
    __syncthreads();
    return incl - v + wsum[w];
}

__global__ __launch_bounds__(256) void scan_a_kernel(
    const int* __restrict__ cnt, int* __restrict__ bsum)
{
    __shared__ int wsum[4];
    int tid = threadIdx.x;
    int i = blockIdx.x * 256 + tid;
    int v = (i < SCAN_N) ? cnt[i] : 0;
#pragma unroll
    for (int d = 32; d >= 1; d >>= 1) v += __shfl_down(v, d, 64);
    if ((tid & 63) == 0) wsum[tid >> 6] = v;
    __syncthreads();
    if (tid == 0) bsum[blockIdx.x] = wsum[0] + wsum[1] + wsum[2] + wsum[3];
}

__global__ __launch_bounds__(512) void scan_b_kernel(
    int* __restrict__ bsum, int* __restrict__ offs_all)
{
    int tid = threadIdx.x;
    int v = (tid < SA_BLOCKS) ? bsum[tid] : 0;
    int excl = block_excl_scan<512>(v, tid);
    if (tid < SA_BLOCKS) bsum[tid] = excl;
    if (tid == SA_BLOCKS - 1) offs_all[SCAN_N] = excl + v;  // = 2*NE
}

__global__ __launch_bounds__(256) void scan_c_kernel(
    int* __restrict__ cnt, const int* __restrict__ bsum,
    int* __restrict__ offs_all)
{
    int tid = threadIdx.x;
    int i = blockIdx.x * 256 + tid;
    int v = (i < SCAN_N) ? cnt[i] : 0;
    int excl = block_excl_scan<256>(v, tid) + bsum[blockIdx.x];
    if (i < SCAN_N) { offs_all[i] = excl; cnt[i] = excl; }
}

__global__ __launch_bounds__(256) void fill2_kernel(
    const int* __restrict__ eidx, int* __restrict__ cursor,
    int2* __restrict__ ordsrc)
{
    int e = blockIdx.x * 256 + threadIdx.x;
    if (e < NE) {
        int s = eidx[e], d = eidx[NE + e];
        int ps = atomicAdd(&cursor[s], 1);
        int pd = atomicAdd(&cursor[NN + d], 1) - NE;
        ordsrc[ps] = make_int2(e, pd);
    }
}

// ---------------------------------------------------------------------------
// Shared fused-edge machinery. Block = 32 src nodes.
//   phase 1: Y[node][k][o] = sum_i row[node,i]*w2[k,i,o] (Y0=b2 at slice 16)
//   phase 2: per out-edge slot: hid=relu(ea@w1+b1); msg=Y0+sum_k hid[k]*Y[k]
//            -> scattered to dst slot (node gather then streams).
// slotnode: uchar LDS map slot->node (kills the per-edge search).
// ---------------------------------------------------------------------------
struct FusedSmem {
    float xl[NPB * 16];
    float Yl[NPB * YSTRIDE];
    int so[NPB + 1];
    unsigned char slotnode[MAXSLOT];
};

__device__ __forceinline__ void fused_core(
    FusedSmem& sm, int tid, int nmax,
    const float* __restrict__ ea,
    const int2* __restrict__ ordsrc,
    const float* __restrict__ w1, const float* __restrict__ b1,
    const float* __restrict__ w2, const float* __restrict__ b2,
    float* __restrict__ msg_out)
{
    int o = tid & 15;

    // slot->node map (32 threads, ~8 writes each)
    if (tid < nmax) {
        int a = sm.so[tid] - sm.so[0], b = sm.so[tid + 1] - sm.so[0];
        for (int j = a; j < b; ++j) sm.slotnode[j] = (unsigned char)tid;
    }

    // phase 1a: thread (k,o) holds its 16 w2 weights, loops nodes
    {
        int k = tid >> 4;
        float w[16];
#pragma unroll
        for (int i = 0; i < 16; ++i) w[i] = w2[k * 256 + i * 16 + o];
        for (int node = 0; node < nmax; ++node) {
            const float4* xr = (const float4*)&sm.xl[node * 16];
            float4 x0 = xr[0], x1 = xr[1], x2 = xr[2], x3 = xr[3];
            float acc = x0.x * w[0] + x0.y * w[1] + x0.z * w[2] + x0.w * w[3]
                      + x1.x * w[4] + x1.y * w[5] + x1.z * w[6] + x1.w * w[7]
                      + x2.x * w[8] + x2.y * w[9] + x2.z * w[10] + x2.w * w[11]
                      + x3.x * w[12] + x3.y * w[13] + x3.z * w[14] + x3.w * w[15];
            sm.Yl[node * YSTRIDE + k * 16 + o] = acc;
        }
    }
    // phase 1b: Y0 (=b2) slice
    {
        float w[16];
#pragma unroll
        for (int i = 0; i < 16; ++i) w[i] = b2[i * 16 + o];
#pragma unroll
        for (int p = 0; p < 2; ++p) {
            int node = p * 16 + (tid >> 4);
            if (node < nmax) {
                const float4* xr = (const float4*)&sm.xl[node * 16];
                float4 x0 = xr[0], x1 = xr[1], x2 = xr[2], x3 = xr[3];
                float acc = x0.x * w[0] + x0.y * w[1] + x0.z * w[2] + x0.w * w[3]
                          + x1.x * w[4] + x1.y * w[5] + x1.z * w[6] + x1.w * w[7]
                          + x2.x * w[8] + x2.y * w[9] + x2.z * w[10] + x2.w * w[11]
                          + x3.x * w[12] + x3.y * w[13] + x3.z * w[14] + x3.w * w[15];
                sm.Yl[node * YSTRIDE + 256 + o] = acc;
            }
        }
    }
    __syncthreads();

    // phase 2: one thread per out-edge slot
    int j0 = sm.so[0], j1 = sm.so[nmax];
    for (int j = j0 + tid; j < j1; j += 256) {
        int node = sm.slotnode[j - j0];
        int2 od = ordsrc[j];
        int e = od.x, pd = od.y;

        const float4* av = (const float4*)(ea + (size_t)e * 8);
        float4 a0 = av[0], a1 = av[1];
        float a[8] = {a0.x, a0.y, a0.z, a0.w, a1.x, a1.y, a1.z, a1.w};

        float hid[16];
#pragma unroll
        for (int jj = 0; jj < 16; ++jj) hid[jj] = b1[jj];
#pragma unroll
        for (int c = 0; c < 8; ++c)
#pragma unroll
            for (int jj = 0; jj < 16; ++jj) hid[jj] += a[c] * w1[c * 16 + jj];
#pragma unroll
        for (int jj = 0; jj < 16; ++jj) hid[jj] = fmaxf(hid[jj], 0.0f);

        const float4* Yr = (const float4*)&sm.Yl[node * YSTRIDE];
        float4 m0 = Yr[64], m1 = Yr[65], m2 = Yr[66], m3 = Yr[67];
#pragma unroll
        for (int k = 0; k < 16; ++k) {
            float hk = hid[k];
            float4 y0 = Yr[k * 4 + 0], y1 = Yr[k * 4 + 1];
            float4 y2 = Yr[k * 4 + 2], y3 = Yr[k * 4 + 3];
            m0.x = fmaf(hk, y0.x, m0.x); m0.y = fmaf(hk, y0.y, m0.y);
            m0.z = fmaf(hk, y0.z, m0.z); m0.w = fmaf(hk, y0.w, m0.w);
            m1.x = fmaf(hk, y1.x, m1.x); m1.y = fmaf(hk, y1.y, m1.y);
            m1.z = fmaf(hk, y1.z, m1.z); m1.w = fmaf(hk, y1.w, m1.w);
            m2.x = fmaf(hk, y2.x, m2.x); m2.y = fmaf(hk, y2.y, m2.y);
            m2.z = fmaf(hk, y2.z, m2.z); m2.w = fmaf(hk, y2.w, m2.w);
            m3.x = fmaf(hk, y3.x, m3.x); m3.y = fmaf(hk, y3.y, m3.y);
            m3.z = fmaf(hk, y3.z, m3.z); m3.w = fmaf(hk, y3.w, m3.w);
        }
        float4* mp = (float4*)(msg_out + (size_t)pd * 16);
        mp[0] = m0; mp[1] = m1; mp[2] = m2; mp[3] = m3;
    }
}

// Layer 1: rows = x (direct stage)
__global__ __launch_bounds__(256, 4) void edge_fused1(
    const float* __restrict__ xin, const float* __restrict__ ea,
    const int2* __restrict__ ordsrc, const int* __restrict__ offs_src,
    const float* __restrict__ w1, const float* __restrict__ b1,
    const float* __restrict__ w2, const float* __restrict__ b2,
    float* __restrict__ msg1)
{
    __shared__ FusedSmem sm;
    int tid = threadIdx.x;
    int n0 = blockIdx.x * NPB;
    int nmax = NN - n0; if (nmax > NPB) nmax = NPB;

#pragma unroll
    for (int p = 0; p < 2; ++p) {
        int idx = p * 256 + tid;
        int node = idx >> 4, i = idx & 15;
        int gn = n0 + node;
        sm.xl[idx] = (gn < NN) ? xin[(size_t)gn * 16 + i] : 0.0f;
    }
    if (tid <= NPB) {
        int idx = n0 + tid; if (idx > NN) idx = NN;
        sm.so[tid] = offs_src[idx];
    }
    __syncthreads();

    fused_core(sm, tid, nmax, ea, ordsrc, w1, b1, w2, b2, msg1);
}

// Layer 2: rows = h1, computed in-block from msg1 (dst-CSR gather + root1),
// also written to global h1 for the final node kernel.
__global__ __launch_bounds__(256, 4) void edge_fused2(
    const float* __restrict__ xin,      // [N,16] original x (for root1 term)
    const float* __restrict__ msg1,     // [E,16] layer-1 messages, dst order
    const int*  __restrict__ offs_dst,  // offs_all+NN (values offset by NE)
    const float* __restrict__ root1, const float* __restrict__ bias1,
    float* __restrict__ h1g,            // [N,16] out
    const float* __restrict__ ea,
    const int2* __restrict__ ordsrc, const int* __restrict__ offs_src,
    const float* __restrict__ w1, const float* __restrict__ b1,
    const float* __restrict__ w2, const float* __restrict__ b2,
    float* __restrict__ msg2)
{
    __shared__ FusedSmem sm;
    int tid = threadIdx.x;
    int n0 = blockIdx.x * NPB;
    int nmax = NN - n0; if (nmax > NPB) nmax = NPB;
    int o = tid & 15;

    // h1 for this block's 32 nodes: gather-mean msg1 + x@root1 + bias1, relu
#pragma unroll
    for (int p = 0; p < 2; ++p) {
        int node = p * 16 + (tid >> 4);
        int gn = n0 + node;
        if (gn < NN) {
            int j0 = offs_dst[gn] - NE, j1 = offs_dst[gn + 1] - NE;
            float sum = 0.0f;
            for (int j = j0; j < j1; ++j) sum += msg1[(size_t)j * 16 + o];
            float inv = 1.0f / (float)((j1 - j0) > 0 ? (j1 - j0) : 1);
            float acc = sum * inv + bias1[o];
            float xo = xin[(size_t)gn * 16 + o];
#pragma unroll
            for (int i = 0; i < 16; ++i)
                acc += __shfl(xo, i, 16) * root1[i * 16 + o];
            float h = fmaxf(acc, 0.0f);
            sm.xl[node * 16 + o] = h;
            h1g[(size_t)gn * 16 + o] = h;
        }
    }
    if (tid <= NPB) {
        int idx = n0 + tid; if (idx > NN) idx = NN;
        sm.so[tid] = offs_src[idx];
    }
    __syncthreads();

    fused_core(sm, tid, nmax, ea, ordsrc, w1, b1, w2, b2, msg2);
}

// Final node kernel: h2 = relu(mean(msg2) + h1@root2 + bias2); out = h2@qw+qb
__global__ __launch_bounds__(256) void node2q_gather(
    const float* __restrict__ h1, const float* __restrict__ msg,
    const int* __restrict__ offs_dst,
    const float* __restrict__ root, const float* __restrict__ bias,
    const float* __restrict__ qw, const float* __restrict__ qb,
    float* __restrict__ out)
{
    int t = blockIdx.x * 256 + threadIdx.x;
    int n = t >> 4, o = t & 15;
    if (n >= NN) return;

    int j0 = offs_dst[n] - NE, j1 = offs_dst[n + 1] - NE;
    float sum = 0.0f;
    for (int j = j0; j < j1; ++j) sum += msg[(size_t)j * 16 + o];
    float inv = 1.0f / (float)((j1 - j0) > 0 ? (j1 - j0) : 1);
    float acc = sum * inv + bias[o];

    float xo = h1[(size_t)n * 16 + o];
#pragma unroll
    for (int i = 0; i < 16; ++i)
        acc += __shfl(xo, i, 16) * root[i * 16 + o];

    float q = fmaxf(acc, 0.0f) * qw[o];
#pragma unroll
    for (int d = 8; d >= 1; d >>= 1) q += __shfl_down(q, d, 16);
    if (o == 0) out[n] = q + qb[0];
}

extern "C" void kernel_launch(void* const* d_in, const int* in_sizes, int n_in,
                              void* d_out, int out_size, void* d_ws, size_t ws_size,
                              hipStream_t stream) {
    const float* x     = (const float*)d_in[0];
    const float* ea    = (const float*)d_in[1];
    const float* e1w1  = (const float*)d_in[2];
    const float* e1b1  = (const float*)d_in[3];
    const float* e1w2  = (const float*)d_in[4];
    const float* e1b2  = (const float*)d_in[5];
    const float* root1 = (const float*)d_in[6];
    const float* bias1 = (const float*)d_in[7];
    const float* e2w1  = (const float*)d_in[8];
    const float* e2b1  = (const float*)d_in[9];
    const float* e2w2  = (const float*)d_in[10];
    const float* e2b2  = (const float*)d_in[11];
    const float* root2 = (const float*)d_in[12];
    const float* bias2 = (const float*)d_in[13];
    const float* qw    = (const float*)d_in[14];
    const float* qb    = (const float*)d_in[15];
    const int*   eidx  = (const int*)d_in[16];

    float* msg1     = (float*)d_ws;                    // 16*NE
    float* msg2     = msg1 + (size_t)16 * NE;          // 16*NE
    float* h1       = msg2 + (size_t)16 * NE;          // 16*NN
    int*   offs_all = (int*)(h1 + (size_t)16 * NN);    // 2*NN+1
    int*   cursor   = offs_all + SCAN_N + 1;           // 2*NN
    int2*  ordsrc   = (int2*)(cursor + SCAN_N);        // NE int2
    int*   bsum     = (int*)(ordsrc + NE);             // 512

    int eblocks = (NE + 255) / 256;
    int gblocks = (NN + NPB - 1) / NPB;    // 1563
    int nblocks = (NN * 16 + 255) / 256;

    // --- CSR build ---
    hipMemsetAsync(cursor, 0, (size_t)SCAN_N * sizeof(int), stream);
    hist2_kernel<<<eblocks, 256, 0, stream>>>(eidx, cursor);
    scan_a_kernel<<<SA_BLOCKS, 256, 0, stream>>>(cursor, bsum);
    scan_b_kernel<<<1, 512, 0, stream>>>(bsum, offs_all);
    scan_c_kernel<<<SA_BLOCKS, 256, 0, stream>>>(cursor, bsum, offs_all);
    fill2_kernel<<<eblocks, 256, 0, stream>>>(eidx, cursor, ordsrc);

    // --- layer 1 edges ---
    edge_fused1<<<gblocks, 256, 0, stream>>>(x, ea, ordsrc, offs_all,
                                             e1w1, e1b1, e1w2, e1b2, msg1);
    // --- layer 2 edges (computes h1 in-block) ---
    edge_fused2<<<gblocks, 256, 0, stream>>>(x, msg1, offs_all + NN, root1,
                                             bias1, h1, ea, ordsrc, offs_all,
                                             e2w1, e2b1, e2w2, e2b2, msg2);
    // --- final node update + q head ---
    node2q_gather<<<nblocks, 256, 0, stream>>>(h1, msg2, offs_all + NN, root2,
                                               bias2, qw, qb, (float*)d_out);
}